// Round 11
// baseline (62.643 us; speedup 1.0000x reference)
//
#include <hip/hip_runtime.h>
#include <hip/hip_bf16.h>

// (B, S, NK, H, D, DM) = (2, 2048, 32, 8, 64, 512)
constexpr int Bb  = 2;
constexpr int Ss  = 2048;
constexpr int NKk = 32;
constexpr int Hh  = 8;
constexpr int DMm = 512;
constexpr int Mm  = Bb * Ss;   // 4096 rows
constexpr int QKV = 1536;      // concat row stride

typedef __attribute__((ext_vector_type(8))) short bf16x8;
typedef __attribute__((ext_vector_type(4))) float f32x4;

__device__ __forceinline__ float b2f(unsigned short u) {
  return __uint_as_float((unsigned)u << 16);
}
__device__ __forceinline__ unsigned short f2b(float f) {
  unsigned u = __float_as_uint(f);
  unsigned r = (u + 0x7fffu + ((u >> 16) & 1u)) >> 16;   // RNE
  return (unsigned short)r;
}
__device__ __forceinline__ void gload_lds16(const ushort* g, ushort* l) {
  __builtin_amdgcn_global_load_lds(
      (const __attribute__((address_space(1))) void*)g,
      (__attribute__((address_space(3))) void*)l, 16, 0, 0);
}

// ---------------------------------------------------------------------------
// Merged conversion kernel. grid (8,8,8), 256 threads.
//  z<4 : weight transpose+convert, W fp32 [k][n] (512x512) -> Wt bf16 [n][k]
//  z>=4: hs fp32 -> Xb bf16 flat
// ---------------------------------------------------------------------------
__global__ __launch_bounds__(256) void cvt_all_k(
    const float* __restrict__ hs,
    const float* __restrict__ Wq, const float* __restrict__ Wk,
    const float* __restrict__ Wv, const float* __restrict__ Wf,
    ushort* __restrict__ Xb, ushort* __restrict__ Wt3, ushort* __restrict__ Wtf)
{
  __shared__ float tile[64][65];
  const int z = blockIdx.z;
  const int t = threadIdx.x;

  if (z >= 4) {
    const int cid = (z - 4) * 64 + blockIdx.x * 8 + blockIdx.y;   // 0..255
    const size_t base8 = (size_t)cid * 1024;                      // uint4 units
#pragma unroll
    for (int it = 0; it < 4; ++it) {
      const size_t i = base8 + it * 256 + t;
      const float4 a = reinterpret_cast<const float4*>(hs)[2 * i];
      const float4 b = reinterpret_cast<const float4*>(hs)[2 * i + 1];
      ushort o[8] = {f2b(a.x), f2b(a.y), f2b(a.z), f2b(a.w),
                     f2b(b.x), f2b(b.y), f2b(b.z), f2b(b.w)};
      reinterpret_cast<uint4*>(Xb)[i] = *reinterpret_cast<uint4*>(o);
    }
    return;
  }

  const float* W = (z == 0) ? Wq : (z == 1) ? Wk : (z == 2) ? Wv : Wf;
  ushort* Wt = (z < 3) ? (Wt3 + (size_t)z * 512 * 512) : Wtf;

  const int k0 = blockIdx.x * 64, n0 = blockIdx.y * 64;
#pragma unroll
  for (int p = 0; p < 4; ++p) {
    const int r = (t >> 4) + p * 16, c = (t & 15) * 4;
    const float4 v = *reinterpret_cast<const float4*>(&W[(size_t)(k0 + r) * 512 + n0 + c]);
    tile[r][c] = v.x; tile[r][c + 1] = v.y; tile[r][c + 2] = v.z; tile[r][c + 3] = v.w;
  }
  __syncthreads();
  const int n = t >> 2, ks = (t & 3) * 16;
  ushort o[16];
#pragma unroll
  for (int i = 0; i < 16; ++i) o[i] = f2b(tile[ks + i][n]);
  *reinterpret_cast<uint4*>(&Wt[(size_t)(n0 + n) * 512 + k0 + ks])     = *reinterpret_cast<uint4*>(&o[0]);
  *reinterpret_cast<uint4*>(&Wt[(size_t)(n0 + n) * 512 + k0 + ks + 8]) = *reinterpret_cast<uint4*>(&o[8]);
}

// ---------------------------------------------------------------------------
// Counted-vmcnt pipelined bf16 MFMA GEMM (round-8 proven), bf16 output.
// BM=128, BN=96, BK=64, K=512 (8 steps). 4 waves (2x2).
// ---------------------------------------------------------------------------
template <int BMv, int BNv>
__global__ __launch_bounds__(256) void gemm_pipe(
    const ushort* __restrict__ Xb, const ushort* __restrict__ Wt,
    ushort* __restrict__ Y, int ldY)
{
  constexpr int MI  = BMv / 32;
  constexpr int NJ  = BNv / 32;
  constexpr int STG = MI + NJ;
  constexpr int ASZ = BMv * 64;
  __shared__ ushort smem[2 * ASZ + 2 * BNv * 64];

  const int bm = blockIdx.x * BMv;
  const int bn = blockIdx.y * BNv;
  const int t  = threadIdx.x;
  const int wave = t >> 6, lane = t & 63;
  const int wm = (wave >> 1) * (BMv / 2);
  const int wn = (wave & 1) * (BNv / 2);

  f32x4 acc[MI][NJ] = {};

  auto stage = [&](int buf, int k0) {
    ushort* A = smem + buf * ASZ;
    ushort* B = smem + 2 * ASZ + buf * (BNv * 64);
#pragma unroll
    for (int p = 0; p < MI; ++p) {
      const int i = p * 256 + t;
      const int row = i >> 3, sb = i & 7;
      gload_lds16(Xb + (size_t)(bm + row) * 512 + k0 + ((sb ^ (row & 7)) << 3),
                  &A[(size_t)(p * 256 + wave * 64) * 8]);
    }
#pragma unroll
    for (int p = 0; p < NJ; ++p) {
      const int i = p * 256 + t;
      const int row = i >> 3, sb = i & 7;
      gload_lds16(Wt + (size_t)(bn + row) * 512 + k0 + ((sb ^ (row & 7)) << 3),
                  &B[(size_t)(p * 256 + wave * 64) * 8]);
    }
  };

  auto compute = [&](int buf) {
    const ushort* A = smem + buf * ASZ;
    const ushort* B = smem + 2 * ASZ + buf * (BNv * 64);
#pragma unroll
    for (int ks = 0; ks < 2; ++ks) {
      const int kb = ks * 4 + (lane >> 4);
      bf16x8 af[MI], bfr[NJ];
#pragma unroll
      for (int i = 0; i < MI; ++i) {
        const int row = wm + i * 16 + (lane & 15);
        af[i] = *reinterpret_cast<const bf16x8*>(&A[row * 64 + ((kb ^ (row & 7)) << 3)]);
      }
#pragma unroll
      for (int j = 0; j < NJ; ++j) {
        const int row = wn + j * 16 + (lane & 15);
        bfr[j] = *reinterpret_cast<const bf16x8*>(&B[row * 64 + ((kb ^ (row & 7)) << 3)]);
      }
#pragma unroll
      for (int i = 0; i < MI; ++i)
#pragma unroll
        for (int j = 0; j < NJ; ++j)
          acc[i][j] = __builtin_amdgcn_mfma_f32_16x16x32_bf16(af[i], bfr[j], acc[i][j], 0, 0, 0);
    }
  };

  stage(0, 0);
  int cur = 0;
#pragma unroll
  for (int i = 0; i < 8; ++i) {
    if (i < 7) {
      stage(cur ^ 1, (i + 1) * 64);
      asm volatile("s_waitcnt vmcnt(%0)" :: "n"(STG) : "memory");
    } else {
      asm volatile("s_waitcnt vmcnt(0)" ::: "memory");
    }
    __builtin_amdgcn_sched_barrier(0);
    __builtin_amdgcn_s_barrier();
    compute(cur);
    __builtin_amdgcn_sched_barrier(0);
    __builtin_amdgcn_s_barrier();
    cur ^= 1;
  }

#pragma unroll
  for (int i = 0; i < MI; ++i)
#pragma unroll
    for (int j = 0; j < NJ; ++j)
#pragma unroll
      for (int r = 0; r < 4; ++r) {
        const int row = wm + i * 16 + (lane >> 4) * 4 + r;
        const int col = wn + j * 16 + (lane & 15);
        smem[row * BNv + col] = f2b(acc[i][j][r]);
      }
  __syncthreads();
  constexpr int CPT = BMv * BNv / 8 / 256;
#pragma unroll
  for (int p = 0; p < CPT; ++p) {
    const int c = p * 256 + t;
    const int row = c / (BNv / 8);
    const int cb  = c % (BNv / 8);
    *reinterpret_cast<uint4*>(&Y[(size_t)(bm + row) * ldY + bn + cb * 8]) =
        *reinterpret_cast<uint4*>(&smem[row * BNv + cb * 8]);
  }
}

// ---------------------------------------------------------------------------
// Sparse gather attention (round-10). One block per (b,s), 256 threads.
// ---------------------------------------------------------------------------
__global__ __launch_bounds__(256) void attn_k6(
    const ushort* __restrict__ qkv, const float* __restrict__ rpe,
    const int* __restrict__ qkm, ushort* __restrict__ ctx)
{
  __shared__ ushort Ks[32 * 512];
  __shared__ float  qs[512];

  const int bs = blockIdx.x;
  const int b  = bs >> 11;
  const int s  = bs & 2047;
  const int t  = threadIdx.x;
  const int wv = t >> 6, lane = t & 63;

  const ushort* qrow = qkv + (size_t)bs * QKV;
  qs[t]       = b2f(qrow[t]);
  qs[t + 256] = b2f(qrow[t + 256]);

#pragma unroll
  for (int r = 0; r < 8; ++r) {
    const int n = r * 4 + wv;
    int im = qkm[s * NKk + n];
    im = im < 0 ? 0 : im;
    const ushort* gsrc = qkv + (size_t)(b * Ss + im) * QKV + 512
                       + ((lane ^ (n & 7)) * 8);
    gload_lds16(gsrc, &Ks[n * 512]);
  }

  const int iv = qkm[s * NKk + (lane & 31)];
  const float rv = rpe[((size_t)bs * NKk + (t & 31)) * Hh + (t >> 5)];

  __syncthreads();

  const ushort* vbase = qkv + (size_t)b * Ss * QKV + 1024;
  const int e = 2 * t;
  uint vvu[32];
#pragma unroll
  for (int n2 = 0; n2 < 32; ++n2) {
    int row = __shfl(iv, (lane & 32) + n2, 64);
    row = row < 0 ? 0 : row;
    vvu[n2] = *reinterpret_cast<const uint*>(&vbase[(size_t)row * QKV + (e & 511)]);
  }

  const int h = t >> 5;
  const int n = t & 31;
  const bool valid = (iv >= 0);

  float2 a2 = make_float2(0.f, 0.f);
#pragma unroll
  for (int j = 0; j < 8; ++j) {
    const int blk = (h * 8 + j) ^ (n & 7);
    const uint4 kk = *reinterpret_cast<const uint4*>(&Ks[n * 512 + blk * 8]);
    const float4 qa = *reinterpret_cast<const float4*>(&qs[h * 64 + j * 8]);
    const float4 qb = *reinterpret_cast<const float4*>(&qs[h * 64 + j * 8 + 4]);
    a2.x += qa.x * __uint_as_float(kk.x << 16);
    a2.y += qa.y * __uint_as_float(kk.x & 0xffff0000u);
    a2.x += qa.z * __uint_as_float(kk.y << 16);
    a2.y += qa.w * __uint_as_float(kk.y & 0xffff0000u);
    a2.x += qb.x * __uint_as_float(kk.z << 16);
    a2.y += qb.y * __uint_as_float(kk.z & 0xffff0000u);
    a2.x += qb.z * __uint_as_float(kk.w << 16);
    a2.y += qb.w * __uint_as_float(kk.w & 0xffff0000u);
  }
  float sc = a2.x + a2.y + rv;
  sc = valid ? sc * 0.125f : -1e30f;

  float mx = sc;
#pragma unroll
  for (int m = 16; m >= 1; m >>= 1) mx = fmaxf(mx, __shfl_xor(mx, m, 32));
  const float p = valid ? __expf(sc - mx) : 0.f;
  float sum = p;
#pragma unroll
  for (int m = 16; m >= 1; m >>= 1) sum += __shfl_xor(sum, m, 32);
  const float pn = (sum > 0.f) ? (p / sum) : 0.f;

  float c0 = 0.f, c1 = 0.f;
#pragma unroll
  for (int n2 = 0; n2 < 32; ++n2) {
    const float a = __shfl(pn, (lane & 32) + n2, 64);
    c0 += a * __uint_as_float(vvu[n2] << 16);
    c1 += a * __uint_as_float(vvu[n2] & 0xffff0000u);
  }
  const uint packed = (uint)f2b(c0) | ((uint)f2b(c1) << 16);
  *reinterpret_cast<uint*>(&ctx[(size_t)bs * 512 + e]) = packed;
}

// ---------------------------------------------------------------------------
// Fused fc + bias + residual + LayerNorm. One block per 16 rows, BN = 512
// (block owns COMPLETE rows -> LN needs no cross-block sync). 256 threads
// (4 waves; wave w covers cols w*128..+127, NJ=8 frags, MI=1). BK=32,
// 16 K-steps, counted-vmcnt double buffer (9 VMEM per stage per wave:
// 8 B-loads + 1 redundant A-load issued by ALL waves for uniform vmcnt).
// LDS B layout [rn][kb][8]: wave b128 frag reads are dense 1 KB  -> no
// conflicts. Epilogue: fp32 tile T[16][516] overlaid on Bs, wave-per-4-rows
// LayerNorm, single write of final out.
// ---------------------------------------------------------------------------
__global__ __launch_bounds__(256) void fc_ln_k(
    const ushort* __restrict__ Xc, const ushort* __restrict__ Wtf,
    float* __restrict__ out, const float* __restrict__ bias,
    const float* __restrict__ resid,
    const float* __restrict__ lng, const float* __restrict__ lnb)
{
  __shared__ ushort Bs[2][512][4][8];   // 64 KB
  __shared__ ushort As[2][16][4][8];    // 2 KB

  const int bm = blockIdx.x * 16;
  const int t  = threadIdx.x;
  const int wv = t >> 6, lane = t & 63;

  f32x4 acc[8] = {};

  auto stage = [&](int buf, int k0) {
    // B: 512 rows x 32 k, slot idx = rn*4 + kb (16B units)
#pragma unroll
    for (int p = 0; p < 8; ++p) {
      const int i = p * 256 + t;           // 0..2047
      const int rn = i >> 2, kb = i & 3;
      gload_lds16(Wtf + (size_t)rn * 512 + k0 + kb * 8,
                  &Bs[buf][0][0][0] + (size_t)(p * 256 + wv * 64) * 8);
    }
    // A: 16 rows x 32 k; all 4 waves redundantly load the same 1 KB
    {
      const int row = lane >> 2, kb = lane & 3;
      gload_lds16(Xc + (size_t)(bm + row) * 512 + k0 + kb * 8,
                  &As[buf][0][0][0]);
    }
  };

  auto compute = [&](int buf) {
    const int kb = lane >> 4, r16 = lane & 15;
    const bf16x8 af = *reinterpret_cast<const bf16x8*>(&As[buf][r16][kb][0]);
#pragma unroll
    for (int j = 0; j < 8; ++j) {
      const int rn = wv * 128 + j * 16 + r16;
      const bf16x8 bf = *reinterpret_cast<const bf16x8*>(&Bs[buf][rn][kb][0]);
      acc[j] = __builtin_amdgcn_mfma_f32_16x16x32_bf16(af, bf, acc[j], 0, 0, 0);
    }
  };

  stage(0, 0);
  int cur = 0;
#pragma unroll
  for (int i = 0; i < 16; ++i) {
    if (i < 15) {
      stage(cur ^ 1, (i + 1) * 32);
      asm volatile("s_waitcnt vmcnt(9)" ::: "memory");
    } else {
      asm volatile("s_waitcnt vmcnt(0)" ::: "memory");
    }
    __builtin_amdgcn_sched_barrier(0);
    __builtin_amdgcn_s_barrier();
    compute(cur);
    __builtin_amdgcn_sched_barrier(0);
    __builtin_amdgcn_s_barrier();
    cur ^= 1;
  }

  // ---- epilogue: bias + residual into fp32 LDS tile, then per-row LN ----
  float* T = reinterpret_cast<float*>(&Bs[0][0][0][0]);   // [16][516]
  const int r4 = lane >> 4, cn = lane & 15;
#pragma unroll
  for (int j = 0; j < 8; ++j) {
    const int col = wv * 128 + j * 16 + cn;
    const float bb = bias[col];
#pragma unroll
    for (int r = 0; r < 4; ++r) {
      const int row = r4 * 4 + r;
      T[row * 516 + col] = acc[j][r] + bb + resid[(size_t)(bm + row) * 512 + col];
    }
  }
  __syncthreads();

#pragma unroll
  for (int rr = 0; rr < 4; ++rr) {
    const int row = wv * 4 + rr;
    const float4 v0 = *reinterpret_cast<const float4*>(&T[row * 516 + lane * 4]);
    const float4 v1 = *reinterpret_cast<const float4*>(&T[row * 516 + 256 + lane * 4]);
    float sum = v0.x + v0.y + v0.z + v0.w + v1.x + v1.y + v1.z + v1.w;
    float sq  = v0.x * v0.x + v0.y * v0.y + v0.z * v0.z + v0.w * v0.w
              + v1.x * v1.x + v1.y * v1.y + v1.z * v1.z + v1.w * v1.w;
#pragma unroll
    for (int m = 32; m >= 1; m >>= 1) {
      sum += __shfl_xor(sum, m, 64);
      sq  += __shfl_xor(sq,  m, 64);
    }
    const float mu  = sum * (1.f / 512.f);
    const float var = sq * (1.f / 512.f) - mu * mu;
    const float rs  = rsqrtf(var + 1e-6f);
    const float4 g0 = reinterpret_cast<const float4*>(lng)[lane];
    const float4 g1 = reinterpret_cast<const float4*>(lng)[lane + 64];
    const float4 b0 = reinterpret_cast<const float4*>(lnb)[lane];
    const float4 b1 = reinterpret_cast<const float4*>(lnb)[lane + 64];
    float4 o0, o1;
    o0.x = (v0.x - mu) * rs * g0.x + b0.x;
    o0.y = (v0.y - mu) * rs * g0.y + b0.y;
    o0.z = (v0.z - mu) * rs * g0.z + b0.z;
    o0.w = (v0.w - mu) * rs * g0.w + b0.w;
    o1.x = (v1.x - mu) * rs * g1.x + b1.x;
    o1.y = (v1.y - mu) * rs * g1.y + b1.y;
    o1.z = (v1.z - mu) * rs * g1.z + b1.z;
    o1.w = (v1.w - mu) * rs * g1.w + b1.w;
    float4* orow = reinterpret_cast<float4*>(out + (size_t)(bm + row) * 512);
    orow[lane]      = o0;
    orow[lane + 64] = o1;
  }
}

extern "C" void kernel_launch(void* const* d_in, const int* in_sizes, int n_in,
                              void* d_out, int out_size, void* d_ws, size_t ws_size,
                              hipStream_t stream) {
  const float* hs  = (const float*)d_in[0];
  const float* rpe = (const float*)d_in[1];
  const int*   qkm = (const int*)d_in[2];
  const float* wq  = (const float*)d_in[4];
  const float* wk  = (const float*)d_in[5];
  const float* wv  = (const float*)d_in[6];
  const float* fcw = (const float*)d_in[7];
  const float* fcb = (const float*)d_in[8];
  const float* lng = (const float*)d_in[9];
  const float* lnb = (const float*)d_in[10];
  float* out = (float*)d_out;

  // workspace (ushort elems): Xb 2M | Wt3 0.75M | Wtf 0.25M | qkv 6M | cxb 2M
  ushort* Xb  = (ushort*)d_ws;
  ushort* Wt3 = Xb  + (size_t)Mm * DMm;
  ushort* Wtf = Wt3 + (size_t)3 * DMm * DMm;
  ushort* qkv = Wtf + (size_t)DMm * DMm;
  ushort* cxb = qkv + (size_t)Mm * QKV;

  cvt_all_k<<<dim3(8, 8, 8), 256, 0, stream>>>(hs, wq, wk, wv, fcw, Xb, Wt3, Wtf);

  // fused QKV GEMM: 128x96 tiles -> 32x16 = 512 blocks = 2.00/CU
  gemm_pipe<128, 96><<<dim3(Mm / 128, QKV / 96), 256, 0, stream>>>(
      Xb, Wt3, qkv, QKV);

  attn_k6<<<Mm, 256, 0, stream>>>(qkv, rpe, qkm, cxb);

  // fused fc + bias + residual + LayerNorm: 256 blocks, 16 rows each
  fc_ln_k<<<Mm / 16, 256, 0, stream>>>(cxb, Wtf, out, fcb, hs, lng, lnb);
}

// Round 12
// 54.872 us; speedup vs baseline: 1.1416x; 1.1416x over previous
//
#include <hip/hip_runtime.h>
#include <hip/hip_bf16.h>

// (B, S, NK, H, D, DM) = (2, 2048, 32, 8, 64, 512)
constexpr int Bb  = 2;
constexpr int Ss  = 2048;
constexpr int NKk = 32;
constexpr int Hh  = 8;
constexpr int DMm = 512;
constexpr int Mm  = Bb * Ss;   // 4096 rows
constexpr int QKV = 1536;      // concat row stride

typedef __attribute__((ext_vector_type(8))) short bf16x8;
typedef __attribute__((ext_vector_type(4))) float f32x4;
typedef _Float16 f16x2 __attribute__((ext_vector_type(2)));

__device__ __forceinline__ float b2f(unsigned short u) {
  return __uint_as_float((unsigned)u << 16);
}
__device__ __forceinline__ unsigned short f2b(float f) {
  unsigned u = __float_as_uint(f);
  unsigned r = (u + 0x7fffu + ((u >> 16) & 1u)) >> 16;   // RNE
  return (unsigned short)r;
}
__device__ __forceinline__ ushort f2h(float f) {
  _Float16 h = (_Float16)f;
  return __builtin_bit_cast(ushort, h);
}
__device__ __forceinline__ void gload_lds16(const ushort* g, ushort* l) {
  __builtin_amdgcn_global_load_lds(
      (const __attribute__((address_space(1))) void*)g,
      (__attribute__((address_space(3))) void*)l, 16, 0, 0);
}
// f16 pair dot with f32 accumulate: v_dot2_f32_f16 if available.
__device__ __forceinline__ float dot2h(uint a2, uint b2, float c) {
#if __has_builtin(__builtin_amdgcn_fdot2)
  return __builtin_amdgcn_fdot2(__builtin_bit_cast(f16x2, a2),
                                __builtin_bit_cast(f16x2, b2), c, false);
#else
  const f16x2 a = __builtin_bit_cast(f16x2, a2);
  const f16x2 b = __builtin_bit_cast(f16x2, b2);
  return c + (float)a.x * (float)b.x + (float)a.y * (float)b.y;
#endif
}

// ---------------------------------------------------------------------------
// Merged conversion kernel. grid (8,8,8), 256 threads.
//  z<4 : weight transpose+convert, W fp32 [k][n] (512x512) -> Wt bf16 [n][k]
//  z>=4: hs fp32 -> Xb bf16 flat
// ---------------------------------------------------------------------------
__global__ __launch_bounds__(256) void cvt_all_k(
    const float* __restrict__ hs,
    const float* __restrict__ Wq, const float* __restrict__ Wk,
    const float* __restrict__ Wv, const float* __restrict__ Wf,
    ushort* __restrict__ Xb, ushort* __restrict__ Wt3, ushort* __restrict__ Wtf)
{
  __shared__ float tile[64][65];
  const int z = blockIdx.z;
  const int t = threadIdx.x;

  if (z >= 4) {
    const int cid = (z - 4) * 64 + blockIdx.x * 8 + blockIdx.y;   // 0..255
    const size_t base8 = (size_t)cid * 1024;                      // uint4 units
#pragma unroll
    for (int it = 0; it < 4; ++it) {
      const size_t i = base8 + it * 256 + t;
      const float4 a = reinterpret_cast<const float4*>(hs)[2 * i];
      const float4 b = reinterpret_cast<const float4*>(hs)[2 * i + 1];
      ushort o[8] = {f2b(a.x), f2b(a.y), f2b(a.z), f2b(a.w),
                     f2b(b.x), f2b(b.y), f2b(b.z), f2b(b.w)};
      reinterpret_cast<uint4*>(Xb)[i] = *reinterpret_cast<uint4*>(o);
    }
    return;
  }

  const float* W = (z == 0) ? Wq : (z == 1) ? Wk : (z == 2) ? Wv : Wf;
  ushort* Wt = (z < 3) ? (Wt3 + (size_t)z * 512 * 512) : Wtf;

  const int k0 = blockIdx.x * 64, n0 = blockIdx.y * 64;
#pragma unroll
  for (int p = 0; p < 4; ++p) {
    const int r = (t >> 4) + p * 16, c = (t & 15) * 4;
    const float4 v = *reinterpret_cast<const float4*>(&W[(size_t)(k0 + r) * 512 + n0 + c]);
    tile[r][c] = v.x; tile[r][c + 1] = v.y; tile[r][c + 2] = v.z; tile[r][c + 3] = v.w;
  }
  __syncthreads();
  const int n = t >> 2, ks = (t & 3) * 16;
  ushort o[16];
#pragma unroll
  for (int i = 0; i < 16; ++i) o[i] = f2b(tile[ks + i][n]);
  *reinterpret_cast<uint4*>(&Wt[(size_t)(n0 + n) * 512 + k0 + ks])     = *reinterpret_cast<uint4*>(&o[0]);
  *reinterpret_cast<uint4*>(&Wt[(size_t)(n0 + n) * 512 + k0 + ks + 8]) = *reinterpret_cast<uint4*>(&o[8]);
}

// ---------------------------------------------------------------------------
// Counted-vmcnt pipelined bf16 MFMA GEMM (round-8 proven). Y = Xb @ Wt^T.
// BM=BMv, BN=BNv, BK=64, K=512 (8 steps). 4 waves (2x2).
// OUTM=1: **f16** output via LDS repack (qkv producer).
// OUTM=0: fp32 + bias + resid epilogue (fc).
// ---------------------------------------------------------------------------
template <int OUTM, int BMv, int BNv>
__global__ __launch_bounds__(256) void gemm_pipe(
    const ushort* __restrict__ Xb, const ushort* __restrict__ Wt,
    void* __restrict__ Yv, const float* __restrict__ bias,
    const float* __restrict__ resid, int ldY)
{
  constexpr int MI  = BMv / 32;
  constexpr int NJ  = BNv / 32;
  constexpr int STG = MI + NJ;
  constexpr int ASZ = BMv * 64;
  __shared__ ushort smem[2 * ASZ + 2 * BNv * 64];

  const int bm = blockIdx.x * BMv;
  const int bn = blockIdx.y * BNv;
  const int t  = threadIdx.x;
  const int wave = t >> 6, lane = t & 63;
  const int wm = (wave >> 1) * (BMv / 2);
  const int wn = (wave & 1) * (BNv / 2);

  f32x4 acc[MI][NJ] = {};

  auto stage = [&](int buf, int k0) {
    ushort* A = smem + buf * ASZ;
    ushort* B = smem + 2 * ASZ + buf * (BNv * 64);
#pragma unroll
    for (int p = 0; p < MI; ++p) {
      const int i = p * 256 + t;
      const int row = i >> 3, sb = i & 7;
      gload_lds16(Xb + (size_t)(bm + row) * 512 + k0 + ((sb ^ (row & 7)) << 3),
                  &A[(size_t)(p * 256 + wave * 64) * 8]);
    }
#pragma unroll
    for (int p = 0; p < NJ; ++p) {
      const int i = p * 256 + t;
      const int row = i >> 3, sb = i & 7;
      gload_lds16(Wt + (size_t)(bn + row) * 512 + k0 + ((sb ^ (row & 7)) << 3),
                  &B[(size_t)(p * 256 + wave * 64) * 8]);
    }
  };

  auto compute = [&](int buf) {
    const ushort* A = smem + buf * ASZ;
    const ushort* B = smem + 2 * ASZ + buf * (BNv * 64);
#pragma unroll
    for (int ks = 0; ks < 2; ++ks) {
      const int kb = ks * 4 + (lane >> 4);
      bf16x8 af[MI], bfr[NJ];
#pragma unroll
      for (int i = 0; i < MI; ++i) {
        const int row = wm + i * 16 + (lane & 15);
        af[i] = *reinterpret_cast<const bf16x8*>(&A[row * 64 + ((kb ^ (row & 7)) << 3)]);
      }
#pragma unroll
      for (int j = 0; j < NJ; ++j) {
        const int row = wn + j * 16 + (lane & 15);
        bfr[j] = *reinterpret_cast<const bf16x8*>(&B[row * 64 + ((kb ^ (row & 7)) << 3)]);
      }
#pragma unroll
      for (int i = 0; i < MI; ++i)
#pragma unroll
        for (int j = 0; j < NJ; ++j)
          acc[i][j] = __builtin_amdgcn_mfma_f32_16x16x32_bf16(af[i], bfr[j], acc[i][j], 0, 0, 0);
    }
  };

  stage(0, 0);
  int cur = 0;
#pragma unroll
  for (int i = 0; i < 8; ++i) {
    if (i < 7) {
      stage(cur ^ 1, (i + 1) * 64);
      asm volatile("s_waitcnt vmcnt(%0)" :: "n"(STG) : "memory");
    } else {
      asm volatile("s_waitcnt vmcnt(0)" ::: "memory");
    }
    __builtin_amdgcn_sched_barrier(0);
    __builtin_amdgcn_s_barrier();
    compute(cur);
    __builtin_amdgcn_sched_barrier(0);
    __builtin_amdgcn_s_barrier();
    cur ^= 1;
  }

  if (OUTM) {
#pragma unroll
    for (int i = 0; i < MI; ++i)
#pragma unroll
      for (int j = 0; j < NJ; ++j)
#pragma unroll
        for (int r = 0; r < 4; ++r) {
          const int row = wm + i * 16 + (lane >> 4) * 4 + r;
          const int col = wn + j * 16 + (lane & 15);
          smem[row * BNv + col] = f2h(acc[i][j][r]);   // f16 out
        }
    __syncthreads();
    ushort* Y = reinterpret_cast<ushort*>(Yv);
    constexpr int CPT = BMv * BNv / 8 / 256;
#pragma unroll
    for (int p = 0; p < CPT; ++p) {
      const int c = p * 256 + t;
      const int row = c / (BNv / 8);
      const int cb  = c % (BNv / 8);
      *reinterpret_cast<uint4*>(&Y[(size_t)(bm + row) * ldY + bn + cb * 8]) =
          *reinterpret_cast<uint4*>(&smem[row * BNv + cb * 8]);
    }
  } else {
    float* Y = reinterpret_cast<float*>(Yv);
#pragma unroll
    for (int i = 0; i < MI; ++i) {
#pragma unroll
      for (int j = 0; j < NJ; ++j) {
        const int m = bm + wm + i * 16 + (lane >> 4) * 4;
        const int n = bn + wn + j * 16 + (lane & 15);
        const float bb = bias[n];
#pragma unroll
        for (int r = 0; r < 4; ++r)
          Y[(size_t)(m + r) * ldY + n] = acc[i][j][r] + bb + resid[(size_t)(m + r) * 512 + n];
      }
    }
  }
}

// ---------------------------------------------------------------------------
// Sparse gather attention, f16 Q/K/V. One block per (b,s), 256 threads.
// K rows staged in LDS (32 KB -> 4 blocks/CU); q kept as packed f16 pairs;
// scores via v_dot2_f32_f16; PV via v_pk_fma_f16 on shfl'd (pn,pn) pairs.
// ctx written as bf16 (fc MFMA input dtype).
// ---------------------------------------------------------------------------
__global__ __launch_bounds__(256) void attn_f16(
    const ushort* __restrict__ qkv, const float* __restrict__ rpe,
    const int* __restrict__ qkm, ushort* __restrict__ ctx)
{
  __shared__ ushort Ks[32 * 512];   // K row n at n*512, 16B-block-swizzled
  __shared__ uint   qs[256];        // 512 f16 as packed pairs

  const int bs = blockIdx.x;
  const int b  = bs >> 11;
  const int s  = bs & 2047;
  const int t  = threadIdx.x;
  const int wv = t >> 6, lane = t & 63;

  qs[t] = *reinterpret_cast<const uint*>(qkv + (size_t)bs * QKV + 2 * t);

#pragma unroll
  for (int r = 0; r < 8; ++r) {
    const int n = r * 4 + wv;                 // wave-uniform row
    int im = qkm[s * NKk + n];
    im = im < 0 ? 0 : im;
    const ushort* gsrc = qkv + (size_t)(b * Ss + im) * QKV + 512
                       + ((lane ^ (n & 7)) * 8);
    gload_lds16(gsrc, &Ks[n * 512]);
  }

  const int iv = qkm[s * NKk + (lane & 31)];
  const float rv = rpe[((size_t)bs * NKk + (t & 31)) * Hh + (t >> 5)];

  __syncthreads();

  // ---- V prefetch (post-barrier; hides under phase-2 compute) ----
  const ushort* vbase = qkv + (size_t)b * Ss * QKV + 1024;
  const int e = 2 * t;                      // ctx elems 2t, 2t+1
  uint vvu[32];
#pragma unroll
  for (int n2 = 0; n2 < 32; ++n2) {
    int row = __shfl(iv, (lane & 32) + n2, 64);
    row = row < 0 ? 0 : row;
    vvu[n2] = *reinterpret_cast<const uint*>(&vbase[(size_t)row * QKV + (e & 511)]);
  }

  // ---- phase 2: scores via f16 dot2 (thread = (h = t>>5, n = t&31)) ----
  const int h = t >> 5;
  const int n = t & 31;
  const bool valid = (iv >= 0);

  float acc0 = 0.f, acc1 = 0.f;
#pragma unroll
  for (int j = 0; j < 8; ++j) {
    const int blk = (h * 8 + j) ^ (n & 7);
    const uint4 kk = *reinterpret_cast<const uint4*>(&Ks[n * 512 + blk * 8]);
    const uint4 qq = *reinterpret_cast<const uint4*>(&qs[h * 32 + j * 4]);
    acc0 = dot2h(qq.x, kk.x, acc0);
    acc1 = dot2h(qq.y, kk.y, acc1);
    acc0 = dot2h(qq.z, kk.z, acc0);
    acc1 = dot2h(qq.w, kk.w, acc1);
  }
  float sc = acc0 + acc1 + rv;
  sc = valid ? sc * 0.125f : -1e30f;

  float mx = sc;
#pragma unroll
  for (int m = 16; m >= 1; m >>= 1) mx = fmaxf(mx, __shfl_xor(mx, m, 32));
  const float p = valid ? __expf(sc - mx) : 0.f;
  float sum = p;
#pragma unroll
  for (int m = 16; m >= 1; m >>= 1) sum += __shfl_xor(sum, m, 32);
  const float pn = (sum > 0.f) ? (p / sum) : 0.f;

  // ---- phase 3: packed f16 FMA (v_pk_fma_f16) ----
  f16x2 a2;
  a2.x = (_Float16)pn;
  a2.y = a2.x;
  const int av = __builtin_bit_cast(int, a2);
  f16x2 c01 = {(_Float16)0.f, (_Float16)0.f};
#pragma unroll
  for (int n2 = 0; n2 < 32; ++n2) {
    const int aw = __shfl(av, (lane & 32) + n2, 64);
    c01 += __builtin_bit_cast(f16x2, aw) * __builtin_bit_cast(f16x2, vvu[n2]);
  }
  const uint packed = (uint)f2b((float)c01.x) | ((uint)f2b((float)c01.y) << 16);
  *reinterpret_cast<uint*>(&ctx[(size_t)bs * 512 + e]) = packed;
}

// ---------------------------------------------------------------------------
// In-place row LayerNorm over DM=512. One wave per row, 4 rows per block.
// ---------------------------------------------------------------------------
__global__ __launch_bounds__(256) void ln_k(
    float* __restrict__ x, const float* __restrict__ g,
    const float* __restrict__ bta)
{
  const int w    = threadIdx.x >> 6;
  const int lane = threadIdx.x & 63;
  const int row  = blockIdx.x * 4 + w;

  float4* xr = reinterpret_cast<float4*>(x + (size_t)row * 512);
  const float4 v0 = xr[lane];
  const float4 v1 = xr[lane + 64];

  float sum = v0.x + v0.y + v0.z + v0.w + v1.x + v1.y + v1.z + v1.w;
  float sq  = v0.x * v0.x + v0.y * v0.y + v0.z * v0.z + v0.w * v0.w
            + v1.x * v1.x + v1.y * v1.y + v1.z * v1.z + v1.w * v1.w;
#pragma unroll
  for (int m = 32; m >= 1; m >>= 1) {
    sum += __shfl_xor(sum, m, 64);
    sq  += __shfl_xor(sq,  m, 64);
  }
  const float mu  = sum * (1.f / 512.f);
  const float var = sq * (1.f / 512.f) - mu * mu;
  const float rs  = rsqrtf(var + 1e-6f);

  const float4 g0 = reinterpret_cast<const float4*>(g)[lane];
  const float4 g1 = reinterpret_cast<const float4*>(g)[lane + 64];
  const float4 b0 = reinterpret_cast<const float4*>(bta)[lane];
  const float4 b1 = reinterpret_cast<const float4*>(bta)[lane + 64];

  float4 o0, o1;
  o0.x = (v0.x - mu) * rs * g0.x + b0.x;
  o0.y = (v0.y - mu) * rs * g0.y + b0.y;
  o0.z = (v0.z - mu) * rs * g0.z + b0.z;
  o0.w = (v0.w - mu) * rs * g0.w + b0.w;
  o1.x = (v1.x - mu) * rs * g1.x + b1.x;
  o1.y = (v1.y - mu) * rs * g1.y + b1.y;
  o1.z = (v1.z - mu) * rs * g1.z + b1.z;
  o1.w = (v1.w - mu) * rs * g1.w + b1.w;
  xr[lane]      = o0;
  xr[lane + 64] = o1;
}

extern "C" void kernel_launch(void* const* d_in, const int* in_sizes, int n_in,
                              void* d_out, int out_size, void* d_ws, size_t ws_size,
                              hipStream_t stream) {
  const float* hs  = (const float*)d_in[0];
  const float* rpe = (const float*)d_in[1];
  const int*   qkm = (const int*)d_in[2];
  const float* wq  = (const float*)d_in[4];
  const float* wk  = (const float*)d_in[5];
  const float* wv  = (const float*)d_in[6];
  const float* fcw = (const float*)d_in[7];
  const float* fcb = (const float*)d_in[8];
  const float* lng = (const float*)d_in[9];
  const float* lnb = (const float*)d_in[10];
  float* out = (float*)d_out;

  // workspace (ushort elems): Xb 2M | Wt3 0.75M | Wtf 0.25M | qkv 6M | cxb 2M
  ushort* Xb  = (ushort*)d_ws;
  ushort* Wt3 = Xb  + (size_t)Mm * DMm;
  ushort* Wtf = Wt3 + (size_t)3 * DMm * DMm;
  ushort* qkv = Wtf + (size_t)DMm * DMm;
  ushort* cxb = qkv + (size_t)Mm * QKV;

  cvt_all_k<<<dim3(8, 8, 8), 256, 0, stream>>>(hs, wq, wk, wv, fcw, Xb, Wt3, Wtf);

  // fused QKV GEMM (f16 output): 128x96 tiles -> 32x16 = 512 blocks = 2/CU
  gemm_pipe<1, 128, 96><<<dim3(Mm / 128, QKV / 96), 256, 0, stream>>>(
      Xb, Wt3, qkv, nullptr, nullptr, QKV);

  attn_f16<<<Mm, 256, 0, stream>>>(qkv, rpe, qkm, cxb);

  // fc GEMM: 128x64 tiles -> 32x8 = 256 blocks
  gemm_pipe<0, 128, 64><<<dim3(Mm / 128, DMm / 64), 256, 0, stream>>>(
      cxb, Wtf, out, fcb, hs, DMm);
  ln_k<<<Mm / 4, 256, 0, stream>>>(out, lng, lnb);
}